// Round 7
// baseline (513.761 us; speedup 1.0000x reference)
//
#include <hip/hip_runtime.h>
#include <stdint.h>

#define NT      360000
#define NTRACE  96
#define MEDK    6000
#define MSTRIDE 3000
#define NW      121      // number of MAD windows per trace
#define HALFW   50       // maxpool half-window (101 total)
#define TOPK    100
#define DETCAP  128      // max detections stored per trace (expected: 0)
#define RATIO_F 10.0f
#define DCHUNKS 24       // detect kernel: chunks per trace (15000 samples each)
#define WPB     4        // windows (waves) per block in mad_kernel
#define NSLOT   24       // float4 slots per lane (24*64*4 = 6144 >= 6000)
#define NF4     1500     // MEDK/4
#define HWORDS  1026     // 2 copies * 513 (stride-513 puts copies in adjacent banks)
#define CMPCAP  2048     // per-wave compaction buffer (MAD bin ~1800+5sigma < 2048)

// ---- float <-> sortable key (total order, -0.0 < +0.0, matches XLA top_k) ----
__device__ __forceinline__ uint32_t f2key(float f) {
    uint32_t u = __float_as_uint(f);
    return u ^ (uint32_t)(((int32_t)u >> 31) | 0x80000000);   // branchless
}
__device__ __forceinline__ float key2f(uint32_t k) {
    uint32_t u = (k & 0x80000000u) ? (k & 0x7fffffffu) : ~k;
    return __uint_as_float(u);
}

// wave-synchronous LDS drain (replaces __syncthreads: hist/cmp are wave-private)
__device__ __forceinline__ void wsync() {
    asm volatile("s_waitcnt lgkmcnt(0)" ::: "memory");
}

// Find bin containing `rank` in a 512-bin 2-copy histogram, wave-local.
// Lane l owns bins {l, 64+l, ..., 448+l}; 8 interleaved shuffle scans.
__device__ __forceinline__ void wbin_select512(const uint32_t* whist, int lane,
                                               uint32_t rank, uint32_t& bin,
                                               uint32_t& subrank, uint32_t& cnt)
{
    uint32_t c[8], s[8];
    #pragma unroll
    for (int j = 0; j < 8; ++j) {
        int b = j * 64 + lane;
        c[j] = whist[b] + whist[513 + b];   // banks (lane)%32: conflict-free
        s[j] = c[j];
    }
    #pragma unroll
    for (int off = 1; off < 64; off <<= 1) {
        #pragma unroll
        for (int j = 0; j < 8; ++j) {
            uint32_t t = __shfl_up(s[j], off);
            if (lane >= off) s[j] += t;
        }
    }
    uint32_t base = 0, fb = 0, fr = 0, fc = 0;
    bool found = false;
    #pragma unroll
    for (int j = 0; j < 8; ++j) {
        uint32_t T    = __shfl(s[j], 63);
        uint32_t incl = base + s[j];
        uint32_t excl = incl - c[j];
        if (rank > excl && rank <= incl) {
            found = true; fb = (uint32_t)(j * 64 + lane); fr = rank - excl; fc = c[j];
        }
        base += T;
    }
    unsigned long long bal = __ballot(found);
    int src = __ffsll(bal) - 1;       // exactly one lane found (total >= rank)
    bin     = __shfl(fb, src);
    subrank = __shfl(fr, src);
    cnt     = __shfl(fc, src);
}

// Exact 3000th-smallest (1-indexed == lower median of 6000), one wave, no block
// barriers. Pass 0: 9-bit (sign+exp) 512-bin histogram from registers; compact
// the winning bin (<=2048 for this data: MAD bin [0.5,1) ~ 1800) into wave LDS;
// passes 1-3 (8+8+7 bits) over the compacted keys. Fallback for cnt>CMPCAP
// re-reads the window from global (exact for arbitrary input, never taken here).
template<bool ABS>
__device__ float wave_select(const float4 (&r)[NSLOT], int lane, float sub,
                             uint32_t* whist, uint32_t* wcmp,
                             const float* xt, int t0)
{
    uint32_t* myh = whist + (lane >> 5) * 513;   // 2 copies, 32 lanes each

    for (int i = lane; i < HWORDS; i += 64) whist[i] = 0;
    wsync();
    #pragma unroll
    for (int k = 0; k < NSLOT; ++k) {
        if (k < 23 || lane < 28) {               // i4 = k*64+lane < 1500
            float vv[4] = {r[k].x, r[k].y, r[k].z, r[k].w};
            #pragma unroll
            for (int e = 0; e < 4; ++e) {
                float v = vv[e];
                if (ABS) v = fabsf(v - sub);
                atomicAdd(&myh[f2key(v) >> 23], 1u);
            }
        }
    }
    wsync();
    uint32_t bin, rank, cnt;
    wbin_select512(whist, lane, 3000u, bin, rank, cnt);
    uint32_t prefix = bin << 23;
    uint32_t pmask  = 0xFF800000u;
    const bool usec = (cnt <= CMPCAP);

    if (usec) {   // ballot-compaction, no atomics (running wave offset in regs)
        uint32_t woff = 0;
        const unsigned long long below = (1ull << lane) - 1ull;
        #pragma unroll
        for (int k = 0; k < NSLOT; ++k) {
            float vv[4] = {r[k].x, r[k].y, r[k].z, r[k].w};
            #pragma unroll
            for (int e = 0; e < 4; ++e) {
                bool valid = (k < 23 || lane < 28);
                uint32_t key = 0; bool m = false;
                if (valid) {
                    float v = vv[e];
                    if (ABS) v = fabsf(v - sub);
                    key = f2key(v);
                    m = ((key >> 23) == bin);
                }
                unsigned long long bal = __ballot(m);
                if (m) wcmp[woff + (uint32_t)__popcll(bal & below)] = key;
                woff += (uint32_t)__popcll(bal);
            }
        }
        wsync();
    }

    #pragma unroll
    for (int pass = 1; pass < 4; ++pass) {
        const int      shift = (pass == 1) ? 15 : (pass == 2) ? 7 : 0;
        const uint32_t bm    = (pass == 3) ? 0x7Fu : 0xFFu;
        for (int i = lane; i < HWORDS; i += 64) whist[i] = 0;
        wsync();
        if (usec) {
            const int n = (int)cnt;
            for (int i = lane; i < n; i += 64) {
                uint32_t key = wcmp[i];
                if ((key & pmask) == prefix)
                    atomicAdd(&myh[(key >> shift) & bm], 1u);
            }
        } else {  // exactness fallback: re-read window from global (L2-resident)
            for (int i = lane; i < MEDK; i += 64) {
                int g  = t0 + i;
                int sg = (g < NT) ? g : (2 * NT - 2 - g);
                float v = xt[sg];
                if (ABS) v = fabsf(v - sub);
                uint32_t key = f2key(v);
                if ((key & pmask) == prefix)
                    atomicAdd(&myh[(key >> shift) & bm], 1u);
            }
        }
        wsync();
        uint32_t b2, r2, c2;
        wbin_select512(whist, lane, rank, b2, r2, c2);
        prefix |= b2 << shift;
        pmask  |= bm << shift;
        rank    = r2;
        wsync();
    }
    return key2f(prefix);
}

__global__ __launch_bounds__(256, 3) void mad_kernel(const float* __restrict__ x,
                                                     float* __restrict__ mad)
{
    __shared__ uint32_t hist_s[WPB * HWORDS];   // 16416 B
    __shared__ uint32_t cmp_s[WPB * CMPCAP];    // 32768 B  (total ~49 KB -> 3 blk/CU)
    const int wv   = threadIdx.x >> 6;
    const int lane = threadIdx.x & 63;
    const int wid  = blockIdx.x * WPB + wv;     // one wave = one window
    const int tr   = wid / NW;
    const int wi   = wid % NW;
    const float* xt = x + (size_t)tr * NT;
    const int t0 = wi * MSTRIDE;

    float4 r[NSLOT];                            // 94-96 window values in regs
    if (t0 + MEDK <= NT) {
        const float4* src4 = (const float4*)(xt + t0);   // t0*4 is 16B-aligned
        #pragma unroll
        for (int k = 0; k < NSLOT; ++k) {
            int i4 = k * 64 + lane;
            r[k] = (i4 < NF4) ? src4[i4] : make_float4(0.f, 0.f, 0.f, 0.f);
        }
    } else {                                    // last window: numpy 'reflect'
        #pragma unroll
        for (int k = 0; k < NSLOT; ++k) {
            int i4 = k * 64 + lane;
            float tmp[4] = {0.f, 0.f, 0.f, 0.f};
            if (i4 < NF4) {
                #pragma unroll
                for (int e = 0; e < 4; ++e) {
                    int g  = t0 + i4 * 4 + e;
                    int sg = (g < NT) ? g : (2 * NT - 2 - g);
                    tmp[e] = xt[sg];
                }
            }
            r[k] = make_float4(tmp[0], tmp[1], tmp[2], tmp[3]);
        }
    }

    uint32_t* whist = hist_s + wv * HWORDS;
    uint32_t* wcmp  = cmp_s  + wv * CMPCAP;
    float med  = wave_select<false>(r, lane, 0.0f, whist, wcmp, xt, t0);
    float madv = wave_select<true >(r, lane, med,  whist, wcmp, xt, t0);
    if (lane == 0) mad[wid] = madv;
}

__global__ __launch_bounds__(256) void detect_kernel(const float* __restrict__ x,
                                                     const float* __restrict__ mad,
                                                     uint32_t* __restrict__ counters,
                                                     uint64_t* __restrict__ det)
{
    __shared__ float smad[NW];
    const int tr = blockIdx.x / DCHUNKS;
    const int ch = blockIdx.x % DCHUNKS;
    const float* xt = x + (size_t)tr * NT;
    for (int i = threadIdx.x; i < NW; i += 256) smad[i] = mad[tr * NW + i];
    __syncthreads();
    const int tbeg = ch * (NT / DCHUNKS);
    const int tend = tbeg + (NT / DCHUNKS);
    const int stride = 256 * 4;
    int t0 = tbeg + threadIdx.x * 4;
    float4 nxt = (t0 < tend) ? *(const float4*)(xt + t0)
                             : make_float4(0.f, 0.f, 0.f, 0.f);
    for (int t = t0; t < tend; t += stride) {
        float4 v4 = nxt;
        int tn = t + stride;
        if (tn < tend) nxt = *(const float4*)(xt + tn);   // prefetch next iter
        float vv[4] = {v4.x, v4.y, v4.z, v4.w};
        #pragma unroll
        for (int k = 0; k < 4; ++k) {
            int   tt = t + k;
            float v  = vv[k];
            // bilinear interp of mad along time (align_corners=False, clamped)
            float pos = ((float)tt + 0.5f) / (float)MSTRIDE - 0.5f;
            pos = fmaxf(pos, 0.0f);
            int   x0 = min((int)floorf(pos), NW - 1);
            int   x1 = min(x0 + 1, NW - 1);
            float wg = pos - (float)x0;
            float m  = smad[x0] * (1.0f - wg) + smad[x1] * wg;
            if (v > RATIO_F * m) {                       // almost never true
                bool ismax = true;
                int lo = max(tt - HALFW, 0), hi = min(tt + HALFW, NT - 1);
                for (int j = lo; j <= hi && ismax; ++j) ismax = (xt[j] <= v);
                if (ismax) {
                    uint32_t slot = atomicAdd(&counters[tr], 1u);
                    if (slot < DETCAP)
                        det[(size_t)tr * DETCAP + slot] =
                            ((uint64_t)f2key(v) << 32) | (uint32_t)(~(uint32_t)tt);
                }
            }
        }
    }
}

__global__ __launch_bounds__(64) void finalize_kernel(const float* __restrict__ x,
                                                      const uint32_t* __restrict__ counters,
                                                      const uint64_t* __restrict__ det,
                                                      float* __restrict__ out)
{
    __shared__ uint64_t sdet[DETCAP];
    __shared__ int sposs[TOPK];
    __shared__ int snegs[TOPK];
    __shared__ int s_np, s_nn;
    const int tr   = blockIdx.x;
    const int lane = threadIdx.x;
    const int D = (int)min(counters[tr], (uint32_t)DETCAP);
    for (int i = lane; i < D; i += 64) sdet[i] = det[(size_t)tr * DETCAP + i];
    if (lane == 0) { s_np = 0; s_nn = 0; }
    __syncthreads();

    const float* xt = x + (size_t)tr * NT;
    // first TOPK non-negative-sign (excluding detections) and first TOPK
    // negative-sign indices, ascending index order (XLA top_k tie semantics:
    // masked = x*0 keeps the sign; +0.0 sorts above -0.0, ties by index)
    for (int base = 0; base < NT; base += 64) {
        int np0 = s_np, nn0 = s_nn;
        if (np0 >= TOPK && nn0 >= TOPK) break;
        int  t     = base + lane;
        bool valid = (t < NT);
        uint32_t bits = valid ? __float_as_uint(xt[t]) : 0u;
        bool nonneg = valid && !(bits >> 31);
        bool neg    = valid &&  (bits >> 31);
        if (nonneg && D > 0) {
            for (int i = 0; i < D; ++i) {
                int dt = (int)(~(uint32_t)(sdet[i] & 0xFFFFFFFFull));
                if (dt == t) { nonneg = false; break; }
            }
        }
        unsigned long long bp = __ballot(nonneg);
        unsigned long long bn = __ballot(neg);
        unsigned long long below = (1ull << lane) - 1ull;
        int pidx = np0 + __popcll(bp & below);
        int nidx = nn0 + __popcll(bn & below);
        if (nonneg && pidx < TOPK) sposs[pidx] = t;
        if (neg    && nidx < TOPK) snegs[nidx] = t;
        __syncthreads();
        if (lane == 0) { s_np = np0 + __popcll(bp); s_nn = nn0 + __popcll(bn); }
        __syncthreads();
    }
    __syncthreads();

    if (lane == 0) {  // sort detections descending by total-order key (D tiny)
        for (int i = 1; i < D; ++i) {
            uint64_t k = sdet[i]; int j = i - 1;
            while (j >= 0 && sdet[j] < k) { sdet[j + 1] = sdet[j]; --j; }
            sdet[j + 1] = k;
        }
    }
    __syncthreads();

    const int nd   = min(D, TOPK);
    const int npos = min(s_np, TOPK);
    float* oscore = out + (size_t)tr * TOPK;
    float* oidx   = out + (size_t)NTRACE * TOPK + (size_t)tr * TOPK;
    for (int j = lane; j < TOPK; j += 64) {
        float sc; int idx;
        if (j < nd) {
            uint64_t k = sdet[j];
            sc  = key2f((uint32_t)(k >> 32));
            idx = (int)(~(uint32_t)(k & 0xFFFFFFFFull));
        } else if (j - nd < npos) {
            sc = 0.0f;  idx = sposs[j - nd];
        } else {
            int jj = j - nd - npos;
            sc = -0.0f; idx = (jj < TOPK) ? snegs[jj] : 0;
        }
        oscore[j] = sc;
        oidx[j]   = (float)idx;   // tuple output buffer is read back as f32
    }
}

extern "C" void kernel_launch(void* const* d_in, const int* in_sizes, int n_in,
                              void* d_out, int out_size, void* d_ws, size_t ws_size,
                              hipStream_t stream)
{
    const float* x = (const float*)d_in[0];
    float* out = (float*)d_out;
    char* ws = (char*)d_ws;
    float*    mad      = (float*)ws;                       // 96*121*4 = 46464 B
    uint32_t* counters = (uint32_t*)(ws + 46464);          // 384 B
    uint64_t* det      = (uint64_t*)(ws + 46464 + 384);    // 96*128*8 B (8-aligned)

    hipMemsetAsync(counters, 0, NTRACE * sizeof(uint32_t), stream);
    hipLaunchKernelGGL(mad_kernel, dim3(NTRACE * NW / WPB), dim3(256), 0, stream, x, mad);
    hipLaunchKernelGGL(detect_kernel, dim3(NTRACE * DCHUNKS), dim3(256), 0, stream, x, mad, counters, det);
    hipLaunchKernelGGL(finalize_kernel, dim3(NTRACE),         dim3(64),  0, stream, x, counters, det, out);
}